// Round 7
// baseline (393.631 us; speedup 1.0000x reference)
//
#include <hip/hip_runtime.h>
#include <stdint.h>
#include <math.h>

// Problem constants
#define BROWS 8192
#define SDIM  512
#define HDIM  512
#define NCOL  8704          // S*(2K+1)
#define EPSK  1e-6f
#define LOG2E  1.442695041f
#define TWOL2E 2.885390082f
#define LN2    0.6931471806f

typedef __attribute__((ext_vector_type(8))) short bf16x8;   // MFMA A/B frag (4 VGPR)
typedef __attribute__((ext_vector_type(4))) short bf16x4;
typedef __attribute__((ext_vector_type(4))) float f32x4;    // MFMA C/D frag

__device__ __forceinline__ unsigned short f2bf(float f) {   // RTNE f32->bf16
    unsigned u = __float_as_uint(f);
    u += 0x7fffu + ((u >> 16) & 1u);
    return (unsigned short)(u >> 16);
}
__device__ __forceinline__ unsigned short f2bf_fast(float f) { // round-half-up (2 inst)
    return (unsigned short)((__float_as_uint(f) + 0x8000u) >> 16);
}
__device__ __forceinline__ float bf2f(unsigned short s) {
    return __uint_as_float(((unsigned)s) << 16);
}
#define EXP2F(x) __builtin_amdgcn_exp2f(x)   // v_exp_f32 (base 2)
#define LOG2F(x) __builtin_amdgcn_logf(x)    // v_log_f32 (base 2)
#define RCPF(x)  __builtin_amdgcn_rcpf(x)

// fast tanh, clamp-free
__device__ __forceinline__ float ftanh(float x) {
    float e = EXP2F(TWOL2E * x);
    return (e - 1.f) * RCPF(e + 1.f);
}
__device__ __forceinline__ float ftanh_l2e(float acc, float bias2L) {
    float e = EXP2F(fmaf(acc, TWOL2E, bias2L));
    return fmaf(e, LOG2E, -LOG2E) * RCPF(e + 1.f);
}

// async global->LDS, 16B per lane (gemm1 staging only now)
#define GLD16(g, l)                                                         \
    __builtin_amdgcn_global_load_lds(                                       \
        (const __attribute__((address_space(1))) void*)(g),                 \
        (__attribute__((address_space(3))) void*)(l), 16, 0, 0)

// ===========================================================================
// FRAGMENT-NATIVE LAYOUTS (the round-7 change):
//  hid_f : per (R16 = row/16, K32 = k/32) a 1KB fragment block:
//          idx = (R16*16 + K32)*512 + ((row&15)*4 + ((k&31)>>3))*8 + (k&7)
//  W2p_f : per (colblk, jg = within-colblk col-group/16, K32) a 1KB block:
//          idx = ((colblk*17 + jg)*16 + K32)*512 + ((col&15)*4 + ((k&31)>>3))*8 + (k&7)
//  A wave loads a fragment as ONE coalesced 16B/lane read at
//          base + ((lane&15)*4 + (lane>>4))*8   (permuted-contiguous 1KB)
//  -> gemm2's K-loop needs NO LDS, NO barriers.
// ===========================================================================

// ---- prep unit: W1 -> W1T bf16 transpose (unit u in [0,256)) --------------
__device__ __forceinline__ void do_w1t_unit(
    int u, int t, const float* __restrict__ W1,
    unsigned short* __restrict__ W1T, short* smem)
{
    float* tile = (float*)smem;               // 32*33 floats
    const int cb = (u & 15) * 32;
    const int rb = (u >> 4) * 32;
    const int ty = t >> 3, tx = (t & 7) * 4;
    float4 v = *(const float4*)&W1[(size_t)(rb + ty) * HDIM + cb + tx];
    tile[ty * 33 + tx + 0] = v.x;
    tile[ty * 33 + tx + 1] = v.y;
    tile[ty * 33 + tx + 2] = v.z;
    tile[ty * 33 + tx + 3] = v.w;
    __syncthreads();
    const int oy = t >> 3, ox = (t & 7) * 4;
    bf16x4 o;
    o[0] = (short)f2bf(tile[(ox + 0) * 33 + oy]);
    o[1] = (short)f2bf(tile[(ox + 1) * 33 + oy]);
    o[2] = (short)f2bf(tile[(ox + 2) * 33 + oy]);
    o[3] = (short)f2bf(tile[(ox + 3) * 33 + oy]);
    *(bf16x4*)&W1T[(size_t)(cb + oy) * SDIM + rb + ox] = o;
}

// ---- prep unit: out tail init (unit u in [0,32)) --------------------------
__device__ __forceinline__ void do_logd_unit(
    int u, int t, const float* __restrict__ logd, float* __restrict__ out)
{
    const int b = u * 256 + t;                // 0..8191
    out[(size_t)BROWS * (2 * SDIM) + b] = logd[b];
}

// ---- prep unit: W2 pack -> W2p_f fragment-native (unit u in [0,2176)) -----
__device__ __forceinline__ void do_pack_unit(
    int u, int t, const float* __restrict__ W2,
    unsigned short* __restrict__ W2p, short* smem)
{
    float* tile = (float*)smem;               // 32*17 floats
    const int ct = u >> 2;                    // 0..543 (16-col chunk)
    const int kq = u & 3;                     // kk quarter
    const int colbase = ct * 16;
    const int colblk = ct / 17;
    const int chunk  = ct - colblk * 17;      // jg (within-colblk col group)
    const int k32 = t >> 3;                   // 0..31 (k within 32)
    const int c2  = (t & 7) * 2;              // 0..14 (col pair)
    const int r   = t >> 4;                   // 0..15 (col within 16)
    const int e2  = (t & 15) * 2;             // 0..30 (k pair)
    for (int kk = kq * 4; kk < kq * 4 + 4; ++kk) {
        float2 v = *(const float2*)&W2[(size_t)(kk * 32 + k32) * NCOL + colbase + c2];
        __syncthreads();                      // protect prior reads of tile
        tile[k32 * 17 + c2 + 0] = v.x;
        tile[k32 * 17 + c2 + 1] = v.y;
        __syncthreads();
        // fragment-native: block (colblk, jg=chunk, K32=kk); within: (r*4+(e2>>3))*8+(e2&7)
        const size_t off = (((size_t)colblk * 17 + chunk) * 16 + kk) * 512
                         + (size_t)(r * 4 + (e2 >> 3)) * 8 + (e2 & 7);
        ushort2 o;
        o.x = f2bf(tile[(e2 + 0) * 17 + r]);
        o.y = f2bf(tile[(e2 + 1) * 17 + r]);
        *(ushort2*)&W2p[off] = o;             // e2&7 even<=6 -> pair stays in 8-run
    }
}

// ---- prep unit: x_a -> out[:, :512] copy (unit u in [0,256)) --------------
__device__ __forceinline__ void do_copy_unit(
    int u, int t, const float* __restrict__ x, float* __restrict__ out)
{
    const float4* xi = (const float4*)x;
    float4* oo = (float4*)out;
    const int base = u * 4096 + t;
#pragma unroll
    for (int k2 = 0; k2 < 16; ++k2) {
        const int f = base + k2 * 256;
        const int row = f >> 7, c4 = f & 127;
        oo[(size_t)row * 256 + c4] = xi[(size_t)row * 256 + c4];
    }
}

// ---- gemm1 tile: hid_f = frag-native bf16(tanh((x_a-0.5)@W1+b1)) ----------
__device__ __forceinline__ void gemm1_tile(
    int flat, int tid, const float* __restrict__ x,
    const unsigned short* __restrict__ W1T, const float* __restrict__ b1,
    unsigned short* __restrict__ hid_f, short* smem)
{
    const int xcd  = flat & 7;
    const int j8   = flat >> 3;
    const int bn   = (j8 & 3) * 128;
    const int bm   = (xcd * 16 + (j8 >> 2)) * 64;

    const int lane = tid & 63;
    const int wave = tid >> 6;
    const int ln15 = lane & 15;
    const int quad = lane >> 4;
    const int wm   = (wave >> 1) * 32;
    const int wn   = (wave & 1) * 64;
    const int brow = lane >> 2;
    const int bsub_sw = (lane & 3) ^ ((lane >> 3) & 3);
    const int arow8   = lane >> 3;
    const int aslot_sw = (lane & 7) ^ (arow8 & 7);
    const int qsw = (quad ^ ((ln15 >> 1) & 3)) * 8;
    const int ag  = ln15 & 7;

    f32x4 acc[2][4];
#pragma unroll
    for (int i = 0; i < 2; i++)
#pragma unroll
        for (int j = 0; j < 4; j++) acc[i][j] = (f32x4){0.f, 0.f, 0.f, 0.f};

    const float* asrc = &x[(size_t)(bm + arow8) * (2 * SDIM) + aslot_sw * 4];
    const unsigned short* bsrc = &W1T[(size_t)(bn + brow) * SDIM + bsub_sw * 8];
    float* AsfB = (float*)smem;               // [2][2048]
    short* BsbB = smem + 8192;                // [2][4096]

    auto issue = [&](int n, int p) {
#pragma unroll
        for (int c = 0; c < 2; ++c) {
            const int ca = wave * 2 + c;
            GLD16(asrc + (size_t)ca * 8 * (2 * SDIM) + n * 32, &AsfB[p * 2048 + ca * 256]);
        }
#pragma unroll
        for (int c = 0; c < 2; ++c) {
            const int cb = wave * 2 + c;
            GLD16(bsrc + (size_t)cb * 16 * SDIM + n * 32, &BsbB[p * 4096 + cb * 512]);
        }
    };

    issue(0, 0);
    for (int n = 0; n < 16; ++n) {
        __syncthreads();
        if (n < 15) issue(n + 1, (n + 1) & 1);
        const float* As = AsfB + (n & 1) * 2048;
        const short* Bs = BsbB + (n & 1) * 4096;

        bf16x8 af[2], bfr[4];
#pragma unroll
        for (int i = 0; i < 2; ++i) {
            const int r = wm + i * 16 + ln15;
            f32x4 a0 = *(const f32x4*)&As[r * 32 + ((2 * quad + 0) ^ ag) * 4];
            f32x4 a1 = *(const f32x4*)&As[r * 32 + ((2 * quad + 1) ^ ag) * 4];
            bf16x8 v;
            v[0] = (short)f2bf_fast(a0[0] - 0.5f); v[1] = (short)f2bf_fast(a0[1] - 0.5f);
            v[2] = (short)f2bf_fast(a0[2] - 0.5f); v[3] = (short)f2bf_fast(a0[3] - 0.5f);
            v[4] = (short)f2bf_fast(a1[0] - 0.5f); v[5] = (short)f2bf_fast(a1[1] - 0.5f);
            v[6] = (short)f2bf_fast(a1[2] - 0.5f); v[7] = (short)f2bf_fast(a1[3] - 0.5f);
            af[i] = v;
        }
#pragma unroll
        for (int j = 0; j < 4; ++j)
            bfr[j] = *(const bf16x8*)&Bs[(wn + j * 16 + ln15) * 32 + qsw];
#pragma unroll
        for (int i = 0; i < 2; ++i)
#pragma unroll
            for (int j = 0; j < 4; ++j)
                acc[i][j] = __builtin_amdgcn_mfma_f32_16x16x32_bf16(af[i], bfr[j], acc[i][j], 0, 0, 0);
    }

    // store into hid_f fragment-native layout
#pragma unroll
    for (int j = 0; j < 4; j++) {
        const int col = bn + wn + j * 16 + ln15;
        const float bias = b1[col];
        const size_t cpart = (size_t)(col >> 5) * 512 + (size_t)((col >> 3) & 3) * 8 + (col & 7);
#pragma unroll
        for (int i = 0; i < 2; i++) {
#pragma unroll
            for (int r = 0; r < 4; r++) {
                const int row = bm + wm + i * 16 + quad * 4 + r;
                const size_t idx = (size_t)(row >> 4) * 8192 + cpart + (size_t)(row & 15) * 32;
                hid_f[idx] = f2bf(ftanh(acc[i][j][r] + bias));
            }
        }
    }
}

// ---- gemm2 tile + spline epilogue: BM=64 x BN=272, NO-LDS K-loop ----------
// Per wave-step: 4 A frags + 4|5 B frags direct global->VGPR (coalesced 1KB
// each), register double-buffered, 16-20 MFMA. No barriers in the K-loop.
__device__ __forceinline__ void gemm2_tile(
    int bm, int colblk, int tid,
    const unsigned short* __restrict__ hid_f, const unsigned short* __restrict__ W2p_f,
    const float* __restrict__ b2, const float* __restrict__ x,
    float* __restrict__ out, short* smem)
{
    const int lane = tid & 63;
    const int wave = tid >> 6;
    const int ln15 = lane & 15;
    const int quad = lane >> 4;
    const int jstart = wave * 4;
    const int bcol = colblk * 272;
    const int voff = (ln15 * 4 + quad) * 8;   // permuted-contiguous lane offset

    f32x4 acc[4][5];
#pragma unroll
    for (int i = 0; i < 4; i++)
#pragma unroll
        for (int j = 0; j < 5; j++) acc[i][j] = (f32x4){0.f, 0.f, 0.f, 0.f};

    const unsigned short* pa = hid_f + (size_t)(bm >> 4) * 8192 + voff;
    const unsigned short* pb = W2p_f + ((size_t)colblk * 17 + jstart) * 8192 + voff;

    // prefetch x_b early (hides under the K-loop)
    const int sp = tid & 15;
    const int r0 = tid >> 4;
    const int sglob = colblk * 16 + sp;
    float xbv[4];
#pragma unroll
    for (int t = 0; t < 4; ++t)
        xbv[t] = x[(size_t)(bm + t * 16 + r0) * (2 * SDIM) + SDIM + sglob];
    float b2v[5];
#pragma unroll
    for (int j = 0; j < 5; ++j)
        b2v[j] = b2[bcol + (jstart + j) * 16 + ln15] * TWOL2E;

#define LDSTEP(A, B, n)                                                         \
    {                                                                           \
        _Pragma("unroll") for (int i_ = 0; i_ < 4; ++i_)                        \
            A[i_] = *(const bf16x8*)(pa + (size_t)i_ * 8192 + (n) * 512);       \
        _Pragma("unroll") for (int j_ = 0; j_ < 4; ++j_)                        \
            B[j_] = *(const bf16x8*)(pb + (size_t)j_ * 8192 + (n) * 512);       \
        if (wave == 3)                                                          \
            B[4] = *(const bf16x8*)(pb + (size_t)4 * 8192 + (n) * 512);         \
    }
#define MMSTEP(A, B)                                                            \
    {                                                                           \
        _Pragma("unroll") for (int i_ = 0; i_ < 4; ++i_)                        \
            _Pragma("unroll") for (int j_ = 0; j_ < 4; ++j_)                    \
                acc[i_][j_] = __builtin_amdgcn_mfma_f32_16x16x32_bf16(          \
                    A[i_], B[j_], acc[i_][j_], 0, 0, 0);                        \
        if (wave == 3)                                                          \
            _Pragma("unroll") for (int i_ = 0; i_ < 4; ++i_)                    \
                acc[i_][4] = __builtin_amdgcn_mfma_f32_16x16x32_bf16(           \
                    A[i_], B[4], acc[i_][4], 0, 0, 0);                          \
    }

    bf16x8 aA[4], bA[5], aB[4], bB[5];
    LDSTEP(aA, bA, 0);
    for (int n = 0; n < 16; n += 2) {
        LDSTEP(aB, bB, n + 1);                // issue next while computing cur
        MMSTEP(aA, bA);
        if (n + 2 < 16) LDSTEP(aA, bA, n + 2);
        MMSTEP(aB, bB);
    }
#undef LDSTEP
#undef MMSTEP

    // ---- phase 1: s = log2e*tanh(acc+bias) -> netS [col][row], stride 68 ---
#define EPI1(JC)                                                                \
    _Pragma("unroll") for (int j = 0; j < (JC); ++j) {                          \
        const int col_l = (jstart + j) * 16 + ln15;                             \
        const float bias2L = b2v[j];                                            \
        _Pragma("unroll") for (int i = 0; i < 4; ++i) {                         \
            bf16x4 o;                                                           \
            _Pragma("unroll") for (int r = 0; r < 4; ++r)                       \
                o[r] = (short)f2bf_fast(ftanh_l2e(acc[i][j][r], bias2L));       \
            *(bf16x4*)&smem[col_l * 68 + i * 16 + quad * 4] = o;                \
        }                                                                       \
    }
    if (wave == 3) { EPI1(5) } else { EPI1(4) }
#undef EPI1
    __syncthreads();

    // ---- phase 2: spline math per (row, spline) ----------------------------
    for (int t = 0; t < 4; ++t) {
        const int row_l = t * 16 + r0;
        const int row = bm + row_l;
        const int cbase = sp * 17 * 68 + row_l;     // netS [col][row]

        float s[17];
#pragma unroll
        for (int c = 0; c < 17; c++)
            s[c] = bf2f((unsigned short)smem[cbase + c * 68]);

        float eh[9], e[8];
#pragma unroll
        for (int j = 0; j < 9; j++) eh[j] = EXP2F(s[j]);
#pragma unroll
        for (int c = 0; c < 8; c++) e[c]  = EXP2F(s[9 + c]);

        float cum_e[8], cum_u[8];
        cum_e[0] = e[0];
        cum_u[0] = e[0] * (eh[0] + eh[1]);
#pragma unroll
        for (int c = 1; c < 8; c++) {
            cum_e[c] = cum_e[c - 1] + e[c];
            cum_u[c] = fmaf(e[c], eh[c] + eh[c + 1], cum_u[c - 1]);
        }
        const float se = cum_e[7];
        const float su = cum_u[7];
        const float thr = xbv[t] * se;

        float selE = e[0], selEH = eh[0], selEH1 = eh[1];
        float selCE = -EPSK * se, selCU = 0.f;
#pragma unroll
        for (int c = 1; c < 8; c++) {
            const bool tt = (cum_e[c - 1] < thr);
            selE   = tt ? e[c]         : selE;
            selEH  = tt ? eh[c]        : selEH;
            selEH1 = tt ? eh[c + 1]    : selEH1;
            selCE  = tt ? cum_e[c - 1] : selCE;
            selCU  = tt ? cum_u[c - 1] : selCU;
        }

        const float alpha = (thr - selCE) * RCPF(selE);
        const float dlt   = selEH1 - selEH;
        const float su_inv = RCPF(su);
        float p = fmaf(2.f * alpha, selE * selEH, selCU);
        p = fmaf(alpha * alpha, selE * dlt, p);
        out[(size_t)row * (2 * SDIM) + SDIM + sglob] = p * su_inv;

        const float g = fmaf(alpha, dlt, selEH) * (2.f * se * su_inv);
        float lg = LOG2F(g);
        lg += __shfl_xor(lg, 1);
        lg += __shfl_xor(lg, 2);
        lg += __shfl_xor(lg, 4);
        lg += __shfl_xor(lg, 8);
        if (sp == 0)
            atomicAdd(&out[(size_t)BROWS * (2 * SDIM) + row], -lg * LN2);
    }
}

// ===========================================================================
// Kernels (round-5 three-kernel structure; fusion abandoned — the ~98us gap
// between sum-of-kernels and dur_us is harness-fixed, proven by round 6).
// ===========================================================================
__global__ __launch_bounds__(256) void prep_a_k(
    const float* __restrict__ W1, unsigned short* __restrict__ W1T,
    const float* __restrict__ logd, float* __restrict__ out)
{
    __shared__ short smem[2112];
    if (blockIdx.x < 256) do_w1t_unit(blockIdx.x, threadIdx.x, W1, W1T, smem);
    else                  do_logd_unit(blockIdx.x - 256, threadIdx.x, logd, out);
}

__global__ __launch_bounds__(256) void mega_k(
    const float* __restrict__ x, const unsigned short* __restrict__ W1T,
    const float* __restrict__ b1, unsigned short* __restrict__ hid_f,
    const float* __restrict__ W2, unsigned short* __restrict__ W2p_f,
    float* __restrict__ out)
{
    __shared__ short smem[16384];             // 32KB (gemm1 staging / pack tile)
    const int bid = blockIdx.x;
    if (bid < 512)        gemm1_tile(bid, threadIdx.x, x, W1T, b1, hid_f, smem);
    else if (bid < 2688)  do_pack_unit(bid - 512, threadIdx.x, W2, W2p_f, smem);
    else                  do_copy_unit(bid - 2688, threadIdx.x, x, out);
}

__global__ __launch_bounds__(256, 3) void gemm2_k(
    const unsigned short* __restrict__ hid_f, const unsigned short* __restrict__ W2p_f,
    const float* __restrict__ b2, const float* __restrict__ x,
    float* __restrict__ out)
{
    __shared__ short smem[18496];             // netS [272][68] = 37KB only
    gemm2_tile(blockIdx.x * 64, blockIdx.y, threadIdx.x, hid_f, W2p_f, b2, x, out, smem);
}

// ---------------------------------------------------------------------------
extern "C" void kernel_launch(void* const* d_in, const int* in_sizes, int n_in,
                              void* d_out, int out_size, void* d_ws, size_t ws_size,
                              hipStream_t stream) {
    const float* x    = (const float*)d_in[0];
    const float* logd = (const float*)d_in[1];
    const float* W1   = (const float*)d_in[2];
    const float* b1   = (const float*)d_in[3];
    const float* W2   = (const float*)d_in[4];
    const float* b2   = (const float*)d_in[5];
    float* out = (float*)d_out;

    // ws layout (~17.9 MiB, unchanged offsets)
    char* ws = (char*)d_ws;
    unsigned short* W1T = (unsigned short*)(ws + 32768);     // 512x512 bf16
    unsigned short* W2p = (unsigned short*)(ws + 557056);    // frag-native 8.9MB
    unsigned short* hid = (unsigned short*)(ws + 9469952);   // frag-native 8.4MB

    prep_a_k<<<288, 256, 0, stream>>>(W1, W1T, logd, out);
    mega_k<<<2944, 256, 0, stream>>>(x, W1T, b1, hid, W2, W2p, out);
    gemm2_k<<<dim3(128, 32), 256, 0, stream>>>(hid, W2p, b2, x, out);
}

// Round 8
// 249.596 us; speedup vs baseline: 1.5771x; 1.5771x over previous
//
#include <hip/hip_runtime.h>
#include <stdint.h>
#include <math.h>

// Problem constants
#define BROWS 8192
#define SDIM  512
#define HDIM  512
#define NCOL  8704          // S*(2K+1)
#define EPSK  1e-6f
#define LOG2E  1.442695041f
#define TWOL2E 2.885390082f
#define LN2    0.6931471806f

typedef __attribute__((ext_vector_type(8))) short bf16x8;   // MFMA A/B frag (4 VGPR)
typedef __attribute__((ext_vector_type(4))) short bf16x4;
typedef __attribute__((ext_vector_type(4))) float f32x4;    // MFMA C/D frag

__device__ __forceinline__ unsigned short f2bf(float f) {   // RTNE f32->bf16
    unsigned u = __float_as_uint(f);
    u += 0x7fffu + ((u >> 16) & 1u);
    return (unsigned short)(u >> 16);
}
__device__ __forceinline__ unsigned short f2bf_fast(float f) { // round-half-up (2 inst)
    return (unsigned short)((__float_as_uint(f) + 0x8000u) >> 16);
}
__device__ __forceinline__ float bf2f(unsigned short s) {
    return __uint_as_float(((unsigned)s) << 16);
}
#define EXP2F(x) __builtin_amdgcn_exp2f(x)   // v_exp_f32 (base 2)
#define LOG2F(x) __builtin_amdgcn_logf(x)    // v_log_f32 (base 2)
#define RCPF(x)  __builtin_amdgcn_rcpf(x)

// fast tanh, clamp-free
__device__ __forceinline__ float ftanh(float x) {
    float e = EXP2F(TWOL2E * x);
    return (e - 1.f) * RCPF(e + 1.f);
}
__device__ __forceinline__ float ftanh_l2e(float acc, float bias2L) {
    float e = EXP2F(fmaf(acc, TWOL2E, bias2L));
    return fmaf(e, LOG2E, -LOG2E) * RCPF(e + 1.f);
}

// async global->LDS, 16B per lane (gemm1 staging only)
#define GLD16(g, l)                                                         \
    __builtin_amdgcn_global_load_lds(                                       \
        (const __attribute__((address_space(1))) void*)(g),                 \
        (__attribute__((address_space(3))) void*)(l), 16, 0, 0)

// ===========================================================================
// FRAGMENT-NATIVE LAYOUTS (unchanged from round 7, verified correct):
//  hid_f : idx = (R16*16 + K32)*512 + ((row&15)*4 + ((k&31)>>3))*8 + (k&7)
//  W2p_f : idx = ((colblk*17 + jg)*16 + K32)*512 + ((col&15)*4 + ((k&31)>>3))*8 + (k&7)
//  Wave loads a fragment as ONE coalesced 16B/lane read at
//          base + ((lane&15)*4 + (lane>>4))*8
// ===========================================================================

// ---- prep unit: W1 -> W1T bf16 transpose (unit u in [0,256)) --------------
__device__ __forceinline__ void do_w1t_unit(
    int u, int t, const float* __restrict__ W1,
    unsigned short* __restrict__ W1T, short* smem)
{
    float* tile = (float*)smem;               // 32*33 floats
    const int cb = (u & 15) * 32;
    const int rb = (u >> 4) * 32;
    const int ty = t >> 3, tx = (t & 7) * 4;
    float4 v = *(const float4*)&W1[(size_t)(rb + ty) * HDIM + cb + tx];
    tile[ty * 33 + tx + 0] = v.x;
    tile[ty * 33 + tx + 1] = v.y;
    tile[ty * 33 + tx + 2] = v.z;
    tile[ty * 33 + tx + 3] = v.w;
    __syncthreads();
    const int oy = t >> 3, ox = (t & 7) * 4;
    bf16x4 o;
    o[0] = (short)f2bf(tile[(ox + 0) * 33 + oy]);
    o[1] = (short)f2bf(tile[(ox + 1) * 33 + oy]);
    o[2] = (short)f2bf(tile[(ox + 2) * 33 + oy]);
    o[3] = (short)f2bf(tile[(ox + 3) * 33 + oy]);
    *(bf16x4*)&W1T[(size_t)(cb + oy) * SDIM + rb + ox] = o;
}

// ---- prep unit: out tail init (unit u in [0,32)) --------------------------
__device__ __forceinline__ void do_logd_unit(
    int u, int t, const float* __restrict__ logd, float* __restrict__ out)
{
    const int b = u * 256 + t;                // 0..8191
    out[(size_t)BROWS * (2 * SDIM) + b] = logd[b];
}

// ---- prep unit: W2 pack -> W2p_f fragment-native (unit u in [0,2176)) -----
__device__ __forceinline__ void do_pack_unit(
    int u, int t, const float* __restrict__ W2,
    unsigned short* __restrict__ W2p, short* smem)
{
    float* tile = (float*)smem;               // 32*17 floats
    const int ct = u >> 2;                    // 0..543 (16-col chunk)
    const int kq = u & 3;                     // kk quarter
    const int colbase = ct * 16;
    const int colblk = ct / 17;
    const int chunk  = ct - colblk * 17;      // jg (within-colblk col group)
    const int k32 = t >> 3;                   // 0..31 (k within 32)
    const int c2  = (t & 7) * 2;              // 0..14 (col pair)
    const int r   = t >> 4;                   // 0..15 (col within 16)
    const int e2  = (t & 15) * 2;             // 0..30 (k pair)
    for (int kk = kq * 4; kk < kq * 4 + 4; ++kk) {
        float2 v = *(const float2*)&W2[(size_t)(kk * 32 + k32) * NCOL + colbase + c2];
        __syncthreads();                      // protect prior reads of tile
        tile[k32 * 17 + c2 + 0] = v.x;
        tile[k32 * 17 + c2 + 1] = v.y;
        __syncthreads();
        const size_t off = (((size_t)colblk * 17 + chunk) * 16 + kk) * 512
                         + (size_t)(r * 4 + (e2 >> 3)) * 8 + (e2 & 7);
        ushort2 o;
        o.x = f2bf(tile[(e2 + 0) * 17 + r]);
        o.y = f2bf(tile[(e2 + 1) * 17 + r]);
        *(ushort2*)&W2p[off] = o;             // e2&7 even<=6 -> pair stays in 8-run
    }
}

// ---- prep unit: x_a -> out[:, :512] copy (unit u in [0,256)) --------------
__device__ __forceinline__ void do_copy_unit(
    int u, int t, const float* __restrict__ x, float* __restrict__ out)
{
    const float4* xi = (const float4*)x;
    float4* oo = (float4*)out;
    const int base = u * 4096 + t;
#pragma unroll
    for (int k2 = 0; k2 < 16; ++k2) {
        const int f = base + k2 * 256;
        const int row = f >> 7, c4 = f & 127;
        oo[(size_t)row * 256 + c4] = xi[(size_t)row * 256 + c4];
    }
}

// ---- gemm1 tile: hid_f = frag-native bf16(tanh((x_a-0.5)@W1+b1)) ----------
__device__ __forceinline__ void gemm1_tile(
    int flat, int tid, const float* __restrict__ x,
    const unsigned short* __restrict__ W1T, const float* __restrict__ b1,
    unsigned short* __restrict__ hid_f, short* smem)
{
    const int xcd  = flat & 7;
    const int j8   = flat >> 3;
    const int bn   = (j8 & 3) * 128;
    const int bm   = (xcd * 16 + (j8 >> 2)) * 64;

    const int lane = tid & 63;
    const int wave = tid >> 6;
    const int ln15 = lane & 15;
    const int quad = lane >> 4;
    const int wm   = (wave >> 1) * 32;
    const int wn   = (wave & 1) * 64;
    const int brow = lane >> 2;
    const int bsub_sw = (lane & 3) ^ ((lane >> 3) & 3);
    const int arow8   = lane >> 3;
    const int aslot_sw = (lane & 7) ^ (arow8 & 7);
    const int qsw = (quad ^ ((ln15 >> 1) & 3)) * 8;
    const int ag  = ln15 & 7;

    f32x4 acc[2][4];
#pragma unroll
    for (int i = 0; i < 2; i++)
#pragma unroll
        for (int j = 0; j < 4; j++) acc[i][j] = (f32x4){0.f, 0.f, 0.f, 0.f};

    const float* asrc = &x[(size_t)(bm + arow8) * (2 * SDIM) + aslot_sw * 4];
    const unsigned short* bsrc = &W1T[(size_t)(bn + brow) * SDIM + bsub_sw * 8];
    float* AsfB = (float*)smem;               // [2][2048]
    short* BsbB = smem + 8192;                // [2][4096]

    auto issue = [&](int n, int p) {
#pragma unroll
        for (int c = 0; c < 2; ++c) {
            const int ca = wave * 2 + c;
            GLD16(asrc + (size_t)ca * 8 * (2 * SDIM) + n * 32, &AsfB[p * 2048 + ca * 256]);
        }
#pragma unroll
        for (int c = 0; c < 2; ++c) {
            const int cb = wave * 2 + c;
            GLD16(bsrc + (size_t)cb * 16 * SDIM + n * 32, &BsbB[p * 4096 + cb * 512]);
        }
    };

    issue(0, 0);
    for (int n = 0; n < 16; ++n) {
        __syncthreads();
        if (n < 15) issue(n + 1, (n + 1) & 1);
        const float* As = AsfB + (n & 1) * 2048;
        const short* Bs = BsbB + (n & 1) * 4096;

        bf16x8 af[2], bfr[4];
#pragma unroll
        for (int i = 0; i < 2; ++i) {
            const int r = wm + i * 16 + ln15;
            f32x4 a0 = *(const f32x4*)&As[r * 32 + ((2 * quad + 0) ^ ag) * 4];
            f32x4 a1 = *(const f32x4*)&As[r * 32 + ((2 * quad + 1) ^ ag) * 4];
            bf16x8 v;
            v[0] = (short)f2bf_fast(a0[0] - 0.5f); v[1] = (short)f2bf_fast(a0[1] - 0.5f);
            v[2] = (short)f2bf_fast(a0[2] - 0.5f); v[3] = (short)f2bf_fast(a0[3] - 0.5f);
            v[4] = (short)f2bf_fast(a1[0] - 0.5f); v[5] = (short)f2bf_fast(a1[1] - 0.5f);
            v[6] = (short)f2bf_fast(a1[2] - 0.5f); v[7] = (short)f2bf_fast(a1[3] - 0.5f);
            af[i] = v;
        }
#pragma unroll
        for (int j = 0; j < 4; ++j)
            bfr[j] = *(const bf16x8*)&Bs[(wn + j * 16 + ln15) * 32 + qsw];
#pragma unroll
        for (int i = 0; i < 2; ++i)
#pragma unroll
            for (int j = 0; j < 4; ++j)
                acc[i][j] = __builtin_amdgcn_mfma_f32_16x16x32_bf16(af[i], bfr[j], acc[i][j], 0, 0, 0);
    }

    // store into hid_f fragment-native layout
#pragma unroll
    for (int j = 0; j < 4; j++) {
        const int col = bn + wn + j * 16 + ln15;
        const float bias = b1[col];
        const size_t cpart = (size_t)(col >> 5) * 512 + (size_t)((col >> 3) & 3) * 8 + (col & 7);
#pragma unroll
        for (int i = 0; i < 2; i++) {
#pragma unroll
            for (int r = 0; r < 4; r++) {
                const int row = bm + wm + i * 16 + quad * 4 + r;
                const size_t idx = (size_t)(row >> 4) * 8192 + cpart + (size_t)(row & 15) * 32;
                hid_f[idx] = f2bf(ftanh(acc[i][j][r] + bias));
            }
        }
    }
}

// ---- gemm2 tile + spline epilogue: BM=64 x BN=272, NO-LDS K-loop ----------
// ROUND-8 FIX: single-buffered fragments (9 live = 36 VGPR; round 7's 18-frag
// reg-dbuf spilled: VGPR_Count=84, 213MB scratch writes). Rolled K-loop
// (#pragma unroll 1) so the compiler cannot re-inflate liveness by cross-step
// pipelining. Budget: acc 80 + frags 36 + addr/epi ~35 => ~150 < 170 cap of
// __launch_bounds__(256,3) -> 3 blocks/CU, 12 waves/CU. Latency model: 9
// coalesced L2 loads (compiler emits counted vmcnt per dependent MFMA), then
// 16-20 independent MFMAs (~310cy); ~50% duty/wave x3 waves/SIMD -> matrix
// pipe near-saturated, zero barriers, zero LDS in the K-loop.
__device__ __forceinline__ void gemm2_tile(
    int bm, int colblk, int tid,
    const unsigned short* __restrict__ hid_f, const unsigned short* __restrict__ W2p_f,
    const float* __restrict__ b2, const float* __restrict__ x,
    float* __restrict__ out, short* smem)
{
    const int lane = tid & 63;
    const int wave = tid >> 6;
    const int ln15 = lane & 15;
    const int quad = lane >> 4;
    const int jstart = wave * 4;
    const int bcol = colblk * 272;
    const int voff = (ln15 * 4 + quad) * 8;   // permuted-contiguous lane offset

    f32x4 acc[4][5];
#pragma unroll
    for (int i = 0; i < 4; i++)
#pragma unroll
        for (int j = 0; j < 5; j++) acc[i][j] = (f32x4){0.f, 0.f, 0.f, 0.f};

    const unsigned short* pa = hid_f + (size_t)(bm >> 4) * 8192 + voff;
    const unsigned short* pb = W2p_f + ((size_t)colblk * 17 + jstart) * 8192 + voff;

    // prefetch x_b + b2 early (hides under the K-loop)
    const int sp = tid & 15;
    const int r0 = tid >> 4;
    const int sglob = colblk * 16 + sp;
    float xbv[4];
#pragma unroll
    for (int t = 0; t < 4; ++t)
        xbv[t] = x[(size_t)(bm + t * 16 + r0) * (2 * SDIM) + SDIM + sglob];
    float b2v[5];
#pragma unroll
    for (int j = 0; j < 5; ++j)
        b2v[j] = b2[bcol + (jstart + j) * 16 + ln15] * TWOL2E;

#pragma unroll 1
    for (int n = 0; n < 16; ++n) {
        bf16x8 af[4], bfr[5];
#pragma unroll
        for (int i = 0; i < 4; ++i)
            af[i] = *(const bf16x8*)(pa + (size_t)i * 8192 + n * 512);
#pragma unroll
        for (int j = 0; j < 4; ++j)
            bfr[j] = *(const bf16x8*)(pb + (size_t)j * 8192 + n * 512);
        if (wave == 3)
            bfr[4] = *(const bf16x8*)(pb + (size_t)4 * 8192 + n * 512);

        __builtin_amdgcn_s_setprio(1);
#pragma unroll
        for (int i = 0; i < 4; ++i)
#pragma unroll
            for (int j = 0; j < 4; ++j)
                acc[i][j] = __builtin_amdgcn_mfma_f32_16x16x32_bf16(
                    af[i], bfr[j], acc[i][j], 0, 0, 0);
        if (wave == 3) {
#pragma unroll
            for (int i = 0; i < 4; ++i)
                acc[i][4] = __builtin_amdgcn_mfma_f32_16x16x32_bf16(
                    af[i], bfr[4], acc[i][4], 0, 0, 0);
        }
        __builtin_amdgcn_s_setprio(0);
    }

    // ---- phase 1: s = log2e*tanh(acc+bias) -> netS [col][row], stride 68 ---
#define EPI1(JC)                                                                \
    _Pragma("unroll") for (int j = 0; j < (JC); ++j) {                          \
        const int col_l = (jstart + j) * 16 + ln15;                             \
        const float bias2L = b2v[j];                                            \
        _Pragma("unroll") for (int i = 0; i < 4; ++i) {                         \
            bf16x4 o;                                                           \
            _Pragma("unroll") for (int r = 0; r < 4; ++r)                       \
                o[r] = (short)f2bf_fast(ftanh_l2e(acc[i][j][r], bias2L));       \
            *(bf16x4*)&smem[col_l * 68 + i * 16 + quad * 4] = o;                \
        }                                                                       \
    }
    if (wave == 3) { EPI1(5) } else { EPI1(4) }
#undef EPI1
    __syncthreads();

    // ---- phase 2: spline math per (row, spline) ----------------------------
    for (int t = 0; t < 4; ++t) {
        const int row_l = t * 16 + r0;
        const int row = bm + row_l;
        const int cbase = sp * 17 * 68 + row_l;     // netS [col][row]

        float s[17];
#pragma unroll
        for (int c = 0; c < 17; c++)
            s[c] = bf2f((unsigned short)smem[cbase + c * 68]);

        float eh[9], e[8];
#pragma unroll
        for (int j = 0; j < 9; j++) eh[j] = EXP2F(s[j]);
#pragma unroll
        for (int c = 0; c < 8; c++) e[c]  = EXP2F(s[9 + c]);

        float cum_e[8], cum_u[8];
        cum_e[0] = e[0];
        cum_u[0] = e[0] * (eh[0] + eh[1]);
#pragma unroll
        for (int c = 1; c < 8; c++) {
            cum_e[c] = cum_e[c - 1] + e[c];
            cum_u[c] = fmaf(e[c], eh[c] + eh[c + 1], cum_u[c - 1]);
        }
        const float se = cum_e[7];
        const float su = cum_u[7];
        const float thr = xbv[t] * se;

        float selE = e[0], selEH = eh[0], selEH1 = eh[1];
        float selCE = -EPSK * se, selCU = 0.f;
#pragma unroll
        for (int c = 1; c < 8; c++) {
            const bool tt = (cum_e[c - 1] < thr);
            selE   = tt ? e[c]         : selE;
            selEH  = tt ? eh[c]        : selEH;
            selEH1 = tt ? eh[c + 1]    : selEH1;
            selCE  = tt ? cum_e[c - 1] : selCE;
            selCU  = tt ? cum_u[c - 1] : selCU;
        }

        const float alpha = (thr - selCE) * RCPF(selE);
        const float dlt   = selEH1 - selEH;
        const float su_inv = RCPF(su);
        float p = fmaf(2.f * alpha, selE * selEH, selCU);
        p = fmaf(alpha * alpha, selE * dlt, p);
        out[(size_t)row * (2 * SDIM) + SDIM + sglob] = p * su_inv;

        const float g = fmaf(alpha, dlt, selEH) * (2.f * se * su_inv);
        float lg = LOG2F(g);
        lg += __shfl_xor(lg, 1);
        lg += __shfl_xor(lg, 2);
        lg += __shfl_xor(lg, 4);
        lg += __shfl_xor(lg, 8);
        if (sp == 0)
            atomicAdd(&out[(size_t)BROWS * (2 * SDIM) + row], -lg * LN2);
    }
}

// ===========================================================================
// Kernels (three-kernel structure; ~98us of dur_us is harness-fixed, r6).
// ===========================================================================
__global__ __launch_bounds__(256) void prep_a_k(
    const float* __restrict__ W1, unsigned short* __restrict__ W1T,
    const float* __restrict__ logd, float* __restrict__ out)
{
    __shared__ short smem[2112];
    if (blockIdx.x < 256) do_w1t_unit(blockIdx.x, threadIdx.x, W1, W1T, smem);
    else                  do_logd_unit(blockIdx.x - 256, threadIdx.x, logd, out);
}

__global__ __launch_bounds__(256) void mega_k(
    const float* __restrict__ x, const unsigned short* __restrict__ W1T,
    const float* __restrict__ b1, unsigned short* __restrict__ hid_f,
    const float* __restrict__ W2, unsigned short* __restrict__ W2p_f,
    float* __restrict__ out)
{
    __shared__ short smem[16384];             // 32KB (gemm1 staging / pack tile)
    const int bid = blockIdx.x;
    if (bid < 512)        gemm1_tile(bid, threadIdx.x, x, W1T, b1, hid_f, smem);
    else if (bid < 2688)  do_pack_unit(bid - 512, threadIdx.x, W2, W2p_f, smem);
    else                  do_copy_unit(bid - 2688, threadIdx.x, x, out);
}

__global__ __launch_bounds__(256, 3) void gemm2_k(
    const unsigned short* __restrict__ hid_f, const unsigned short* __restrict__ W2p_f,
    const float* __restrict__ b2, const float* __restrict__ x,
    float* __restrict__ out)
{
    __shared__ short smem[18496];             // netS [272][68] = 37KB only
    gemm2_tile(blockIdx.x * 64, blockIdx.y, threadIdx.x, hid_f, W2p_f, b2, x, out, smem);
}

// ---------------------------------------------------------------------------
extern "C" void kernel_launch(void* const* d_in, const int* in_sizes, int n_in,
                              void* d_out, int out_size, void* d_ws, size_t ws_size,
                              hipStream_t stream) {
    const float* x    = (const float*)d_in[0];
    const float* logd = (const float*)d_in[1];
    const float* W1   = (const float*)d_in[2];
    const float* b1   = (const float*)d_in[3];
    const float* W2   = (const float*)d_in[4];
    const float* b2   = (const float*)d_in[5];
    float* out = (float*)d_out;

    // ws layout (~17.9 MiB, unchanged offsets)
    char* ws = (char*)d_ws;
    unsigned short* W1T = (unsigned short*)(ws + 32768);     // 512x512 bf16
    unsigned short* W2p = (unsigned short*)(ws + 557056);    // frag-native 8.9MB
    unsigned short* hid = (unsigned short*)(ws + 9469952);   // frag-native 8.4MB

    prep_a_k<<<288, 256, 0, stream>>>(W1, W1T, logd, out);
    mega_k<<<2944, 256, 0, stream>>>(x, W1T, b1, hid, W2, W2p, out);
    gemm2_k<<<dim3(128, 32), 256, 0, stream>>>(hid, W2p, b2, x, out);
}

// Round 9
// 223.903 us; speedup vs baseline: 1.7580x; 1.1147x over previous
//
#include <hip/hip_runtime.h>
#include <stdint.h>
#include <math.h>

// Problem constants
#define BROWS 8192
#define SDIM  512
#define HDIM  512
#define NCOL  8704          // S*(2K+1)
#define EPSK  1e-6f
#define LOG2E  1.442695041f
#define TWOL2E 2.885390082f
#define LN2    0.6931471806f

typedef __attribute__((ext_vector_type(8))) short bf16x8;   // MFMA A/B frag (4 VGPR)
typedef __attribute__((ext_vector_type(4))) short bf16x4;
typedef __attribute__((ext_vector_type(4))) float f32x4;    // MFMA C/D frag

__device__ __forceinline__ unsigned short f2bf(float f) {   // RTNE f32->bf16
    unsigned u = __float_as_uint(f);
    u += 0x7fffu + ((u >> 16) & 1u);
    return (unsigned short)(u >> 16);
}
__device__ __forceinline__ unsigned short f2bf_fast(float f) { // round-half-up (2 inst)
    return (unsigned short)((__float_as_uint(f) + 0x8000u) >> 16);
}
__device__ __forceinline__ float bf2f(unsigned short s) {
    return __uint_as_float(((unsigned)s) << 16);
}
#define EXP2F(x) __builtin_amdgcn_exp2f(x)   // v_exp_f32 (base 2)
#define LOG2F(x) __builtin_amdgcn_logf(x)    // v_log_f32 (base 2)
#define RCPF(x)  __builtin_amdgcn_rcpf(x)

// fast tanh, clamp-free
__device__ __forceinline__ float ftanh(float x) {
    float e = EXP2F(TWOL2E * x);
    return (e - 1.f) * RCPF(e + 1.f);
}
__device__ __forceinline__ float ftanh_l2e(float acc, float bias2L) {
    float e = EXP2F(fmaf(acc, TWOL2E, bias2L));
    return fmaf(e, LOG2E, -LOG2E) * RCPF(e + 1.f);
}

// async global->LDS, 16B per lane
#define GLD16(g, l)                                                         \
    __builtin_amdgcn_global_load_lds(                                       \
        (const __attribute__((address_space(1))) void*)(g),                 \
        (__attribute__((address_space(3))) void*)(l), 16, 0, 0)

// ===========================================================================
// FRAGMENT-NATIVE LAYOUTS (unchanged, verified):
//  hid_f : idx = (R16*16 + K32)*512 + ((row&15)*4 + ((k&31)>>3))*8 + (k&7)
//  W2p_f : idx = ((colblk*17 + jg)*16 + K32)*512 + ((col&15)*4 + ((k&31)>>3))*8 + (k&7)
//  MFMA lane l consumes 16B slot p(l) = (l&15)*4 + (l>>4) of each 1KB block.
// ROUND-9: gemm2 A-operand staged to LDS once per K-half with slot involution
//  sigma(m) = m ^ ((m>>2)&3)  (LDS[m] = G[sigma(m)]; read slot q(l) =
//  p(l) ^ (l&3); sigma(q(l)) == p(l) -> bit-identical fragments, and the
//  read phase covers all 8 bank-quads (4/bank = ds_read_b128 minimum).
// ===========================================================================

// ---- prep unit: W1 -> W1T bf16 transpose (unit u in [0,256)) --------------
__device__ __forceinline__ void do_w1t_unit(
    int u, int t, const float* __restrict__ W1,
    unsigned short* __restrict__ W1T, short* smem)
{
    float* tile = (float*)smem;               // 32*33 floats
    const int cb = (u & 15) * 32;
    const int rb = (u >> 4) * 32;
    const int ty = t >> 3, tx = (t & 7) * 4;
    float4 v = *(const float4*)&W1[(size_t)(rb + ty) * HDIM + cb + tx];
    tile[ty * 33 + tx + 0] = v.x;
    tile[ty * 33 + tx + 1] = v.y;
    tile[ty * 33 + tx + 2] = v.z;
    tile[ty * 33 + tx + 3] = v.w;
    __syncthreads();
    const int oy = t >> 3, ox = (t & 7) * 4;
    bf16x4 o;
    o[0] = (short)f2bf(tile[(ox + 0) * 33 + oy]);
    o[1] = (short)f2bf(tile[(ox + 1) * 33 + oy]);
    o[2] = (short)f2bf(tile[(ox + 2) * 33 + oy]);
    o[3] = (short)f2bf(tile[(ox + 3) * 33 + oy]);
    *(bf16x4*)&W1T[(size_t)(cb + oy) * SDIM + rb + ox] = o;
}

// ---- prep unit: out tail init (unit u in [0,32)) --------------------------
__device__ __forceinline__ void do_logd_unit(
    int u, int t, const float* __restrict__ logd, float* __restrict__ out)
{
    const int b = u * 256 + t;                // 0..8191
    out[(size_t)BROWS * (2 * SDIM) + b] = logd[b];
}

// ---- prep unit: W2 pack -> W2p_f fragment-native (unit u in [0,2176)) -----
__device__ __forceinline__ void do_pack_unit(
    int u, int t, const float* __restrict__ W2,
    unsigned short* __restrict__ W2p, short* smem)
{
    float* tile = (float*)smem;               // 32*17 floats
    const int ct = u >> 2;                    // 0..543 (16-col chunk)
    const int kq = u & 3;                     // kk quarter
    const int colbase = ct * 16;
    const int colblk = ct / 17;
    const int chunk  = ct - colblk * 17;      // jg (within-colblk col group)
    const int k32 = t >> 3;                   // 0..31 (k within 32)
    const int c2  = (t & 7) * 2;              // 0..14 (col pair)
    const int r   = t >> 4;                   // 0..15 (col within 16)
    const int e2  = (t & 15) * 2;             // 0..30 (k pair)
    for (int kk = kq * 4; kk < kq * 4 + 4; ++kk) {
        float2 v = *(const float2*)&W2[(size_t)(kk * 32 + k32) * NCOL + colbase + c2];
        __syncthreads();                      // protect prior reads of tile
        tile[k32 * 17 + c2 + 0] = v.x;
        tile[k32 * 17 + c2 + 1] = v.y;
        __syncthreads();
        const size_t off = (((size_t)colblk * 17 + chunk) * 16 + kk) * 512
                         + (size_t)(r * 4 + (e2 >> 3)) * 8 + (e2 & 7);
        ushort2 o;
        o.x = f2bf(tile[(e2 + 0) * 17 + r]);
        o.y = f2bf(tile[(e2 + 1) * 17 + r]);
        *(ushort2*)&W2p[off] = o;             // e2&7 even<=6 -> pair stays in 8-run
    }
}

// ---- prep unit: x_a -> out[:, :512] copy (unit u in [0,256)) --------------
__device__ __forceinline__ void do_copy_unit(
    int u, int t, const float* __restrict__ x, float* __restrict__ out)
{
    const float4* xi = (const float4*)x;
    float4* oo = (float4*)out;
    const int base = u * 4096 + t;
#pragma unroll
    for (int k2 = 0; k2 < 16; ++k2) {
        const int f = base + k2 * 256;
        const int row = f >> 7, c4 = f & 127;
        oo[(size_t)row * 256 + c4] = xi[(size_t)row * 256 + c4];
    }
}

// ---- gemm1 tile: hid_f = frag-native bf16(tanh((x_a-0.5)@W1+b1)) ----------
__device__ __forceinline__ void gemm1_tile(
    int flat, int tid, const float* __restrict__ x,
    const unsigned short* __restrict__ W1T, const float* __restrict__ b1,
    unsigned short* __restrict__ hid_f, short* smem)
{
    const int xcd  = flat & 7;
    const int j8   = flat >> 3;
    const int bn   = (j8 & 3) * 128;
    const int bm   = (xcd * 16 + (j8 >> 2)) * 64;

    const int lane = tid & 63;
    const int wave = tid >> 6;
    const int ln15 = lane & 15;
    const int quad = lane >> 4;
    const int wm   = (wave >> 1) * 32;
    const int wn   = (wave & 1) * 64;
    const int brow = lane >> 2;
    const int bsub_sw = (lane & 3) ^ ((lane >> 3) & 3);
    const int arow8   = lane >> 3;
    const int aslot_sw = (lane & 7) ^ (arow8 & 7);
    const int qsw = (quad ^ ((ln15 >> 1) & 3)) * 8;
    const int ag  = ln15 & 7;

    f32x4 acc[2][4];
#pragma unroll
    for (int i = 0; i < 2; i++)
#pragma unroll
        for (int j = 0; j < 4; j++) acc[i][j] = (f32x4){0.f, 0.f, 0.f, 0.f};

    const float* asrc = &x[(size_t)(bm + arow8) * (2 * SDIM) + aslot_sw * 4];
    const unsigned short* bsrc = &W1T[(size_t)(bn + brow) * SDIM + bsub_sw * 8];
    float* AsfB = (float*)smem;               // [2][2048]
    short* BsbB = smem + 8192;                // [2][4096]

    auto issue = [&](int n, int p) {
#pragma unroll
        for (int c = 0; c < 2; ++c) {
            const int ca = wave * 2 + c;
            GLD16(asrc + (size_t)ca * 8 * (2 * SDIM) + n * 32, &AsfB[p * 2048 + ca * 256]);
        }
#pragma unroll
        for (int c = 0; c < 2; ++c) {
            const int cb = wave * 2 + c;
            GLD16(bsrc + (size_t)cb * 16 * SDIM + n * 32, &BsbB[p * 4096 + cb * 512]);
        }
    };

    issue(0, 0);
    for (int n = 0; n < 16; ++n) {
        __syncthreads();
        if (n < 15) issue(n + 1, (n + 1) & 1);
        const float* As = AsfB + (n & 1) * 2048;
        const short* Bs = BsbB + (n & 1) * 4096;

        bf16x8 af[2], bfr[4];
#pragma unroll
        for (int i = 0; i < 2; ++i) {
            const int r = wm + i * 16 + ln15;
            f32x4 a0 = *(const f32x4*)&As[r * 32 + ((2 * quad + 0) ^ ag) * 4];
            f32x4 a1 = *(const f32x4*)&As[r * 32 + ((2 * quad + 1) ^ ag) * 4];
            bf16x8 v;
            v[0] = (short)f2bf_fast(a0[0] - 0.5f); v[1] = (short)f2bf_fast(a0[1] - 0.5f);
            v[2] = (short)f2bf_fast(a0[2] - 0.5f); v[3] = (short)f2bf_fast(a0[3] - 0.5f);
            v[4] = (short)f2bf_fast(a1[0] - 0.5f); v[5] = (short)f2bf_fast(a1[1] - 0.5f);
            v[6] = (short)f2bf_fast(a1[2] - 0.5f); v[7] = (short)f2bf_fast(a1[3] - 0.5f);
            af[i] = v;
        }
#pragma unroll
        for (int j = 0; j < 4; ++j)
            bfr[j] = *(const bf16x8*)&Bs[(wn + j * 16 + ln15) * 32 + qsw];
#pragma unroll
        for (int i = 0; i < 2; ++i)
#pragma unroll
            for (int j = 0; j < 4; ++j)
                acc[i][j] = __builtin_amdgcn_mfma_f32_16x16x32_bf16(af[i], bfr[j], acc[i][j], 0, 0, 0);
    }

    // store into hid_f fragment-native layout
#pragma unroll
    for (int j = 0; j < 4; j++) {
        const int col = bn + wn + j * 16 + ln15;
        const float bias = b1[col];
        const size_t cpart = (size_t)(col >> 5) * 512 + (size_t)((col >> 3) & 3) * 8 + (col & 7);
#pragma unroll
        for (int i = 0; i < 2; i++) {
#pragma unroll
            for (int r = 0; r < 4; r++) {
                const int row = bm + wm + i * 16 + quad * 4 + r;
                const size_t idx = (size_t)(row >> 4) * 8192 + cpart + (size_t)(row & 15) * 32;
                hid_f[idx] = f2bf(ftanh(acc[i][j][r] + bias));
            }
        }
    }
}

// ---- gemm2 tile: A from LDS (block-staged per K-half), B direct global ----
__device__ __forceinline__ void gemm2_tile(
    int bm, int colblk, int tid,
    const unsigned short* __restrict__ hid_f, const unsigned short* __restrict__ W2p_f,
    const float* __restrict__ b2, const float* __restrict__ x,
    float* __restrict__ out, short* smem)
{
    const int lane = tid & 63;
    const int wave = tid >> 6;
    const int ln15 = lane & 15;
    const int quad = lane >> 4;
    const int jstart = wave * 4;
    const int bcol = colblk * 272;
    // global-read slot p(l), LDS-read slot q(l) = p ^ (l&3), stage src sigma(l)
    const int voff  = (ln15 * 4 + quad) * 8;                 // p(l)*8 shorts
    const int qoff  = ((ln15 * 4 + quad) ^ (lane & 3)) * 8;  // q(l)*8 shorts
    const int soff  = (lane ^ ((lane >> 2) & 3)) * 8;        // sigma(l)*8 shorts

    f32x4 acc[4][5];
#pragma unroll
    for (int i = 0; i < 4; i++)
#pragma unroll
        for (int j = 0; j < 5; j++) acc[i][j] = (f32x4){0.f, 0.f, 0.f, 0.f};

    const unsigned short* pa = hid_f + (size_t)(bm >> 4) * 8192;  // 4 R16 blocks
    const unsigned short* pb = W2p_f + ((size_t)colblk * 17 + jstart) * 8192 + voff;

    // stage A K-half h into smem[0..16384): 32 frags x 1KB; thread t=w*64+l,
    // iter c: frag f = c*4 + w (wave-uniform), LDS[f][l] = G_f[sigma(l)]
    auto stageA = [&](int h) {
#pragma unroll
        for (int c = 0; c < 8; ++c) {
            const int f = c * 4 + wave;               // 0..31
            const int i = f & 3, nn = f >> 2;
            GLD16(pa + (size_t)i * 8192 + (size_t)(h * 8 + nn) * 512 + soff,
                  &smem[f * 512]);
        }
    };

    // prefetch x_b + b2 early (hides under staging)
    const int sp = tid & 15;
    const int r0 = tid >> 4;
    const int sglob = colblk * 16 + sp;
    stageA(0);
    float xbv[4];
#pragma unroll
    for (int t = 0; t < 4; ++t)
        xbv[t] = x[(size_t)(bm + t * 16 + r0) * (2 * SDIM) + SDIM + sglob];
    float b2v[5];
#pragma unroll
    for (int j = 0; j < 5; ++j)
        b2v[j] = b2[bcol + (jstart + j) * 16 + ln15] * TWOL2E;

#pragma unroll 1
    for (int h = 0; h < 2; ++h) {
        if (h == 1) { __syncthreads(); stageA(1); }   // all half0 reads done
        __syncthreads();                              // staged half visible
#pragma unroll 1
        for (int nn = 0; nn < 8; ++nn) {
            const int n = h * 8 + nn;
            bf16x8 bfr[5], af[4];
#pragma unroll
            for (int j = 0; j < 4; ++j)               // B first: global latency
                bfr[j] = *(const bf16x8*)(pb + (size_t)j * 8192 + n * 512);
            if (wave == 3)
                bfr[4] = *(const bf16x8*)(pb + (size_t)4 * 8192 + n * 512);
#pragma unroll
            for (int i = 0; i < 4; ++i)               // A from LDS (~120cy)
                af[i] = *(const bf16x8*)&smem[(nn * 4 + i) * 512 + qoff];

            __builtin_amdgcn_s_setprio(1);
#pragma unroll
            for (int i = 0; i < 4; ++i)
#pragma unroll
                for (int j = 0; j < 4; ++j)
                    acc[i][j] = __builtin_amdgcn_mfma_f32_16x16x32_bf16(
                        af[i], bfr[j], acc[i][j], 0, 0, 0);
            if (wave == 3) {
#pragma unroll
                for (int i = 0; i < 4; ++i)
                    acc[i][4] = __builtin_amdgcn_mfma_f32_16x16x32_bf16(
                        af[i], bfr[4], acc[i][4], 0, 0, 0);
            }
            __builtin_amdgcn_s_setprio(0);
        }
    }

    // ---- phase 1: s = log2e*tanh(acc+bias) -> netS [col][row], stride 68 ---
    __syncthreads();                          // K-loop LDS reads done (aliasing)
#define EPI1(JC)                                                                \
    _Pragma("unroll") for (int j = 0; j < (JC); ++j) {                          \
        const int col_l = (jstart + j) * 16 + ln15;                             \
        const float bias2L = b2v[j];                                            \
        _Pragma("unroll") for (int i = 0; i < 4; ++i) {                         \
            bf16x4 o;                                                           \
            _Pragma("unroll") for (int r = 0; r < 4; ++r)                       \
                o[r] = (short)f2bf_fast(ftanh_l2e(acc[i][j][r], bias2L));       \
            *(bf16x4*)&smem[col_l * 68 + i * 16 + quad * 4] = o;                \
        }                                                                       \
    }
    if (wave == 3) { EPI1(5) } else { EPI1(4) }
#undef EPI1
    __syncthreads();

    // ---- phase 2: spline math per (row, spline) ----------------------------
    for (int t = 0; t < 4; ++t) {
        const int row_l = t * 16 + r0;
        const int row = bm + row_l;
        const int cbase = sp * 17 * 68 + row_l;     // netS [col][row]

        float s[17];
#pragma unroll
        for (int c = 0; c < 17; c++)
            s[c] = bf2f((unsigned short)smem[cbase + c * 68]);

        float eh[9], e[8];
#pragma unroll
        for (int j = 0; j < 9; j++) eh[j] = EXP2F(s[j]);
#pragma unroll
        for (int c = 0; c < 8; c++) e[c]  = EXP2F(s[9 + c]);

        float cum_e[8], cum_u[8];
        cum_e[0] = e[0];
        cum_u[0] = e[0] * (eh[0] + eh[1]);
#pragma unroll
        for (int c = 1; c < 8; c++) {
            cum_e[c] = cum_e[c - 1] + e[c];
            cum_u[c] = fmaf(e[c], eh[c] + eh[c + 1], cum_u[c - 1]);
        }
        const float se = cum_e[7];
        const float su = cum_u[7];
        const float thr = xbv[t] * se;

        float selE = e[0], selEH = eh[0], selEH1 = eh[1];
        float selCE = -EPSK * se, selCU = 0.f;
#pragma unroll
        for (int c = 1; c < 8; c++) {
            const bool tt = (cum_e[c - 1] < thr);
            selE   = tt ? e[c]         : selE;
            selEH  = tt ? eh[c]        : selEH;
            selEH1 = tt ? eh[c + 1]    : selEH1;
            selCE  = tt ? cum_e[c - 1] : selCE;
            selCU  = tt ? cum_u[c - 1] : selCU;
        }

        const float alpha = (thr - selCE) * RCPF(selE);
        const float dlt   = selEH1 - selEH;
        const float su_inv = RCPF(su);
        float p = fmaf(2.f * alpha, selE * selEH, selCU);
        p = fmaf(alpha * alpha, selE * dlt, p);
        out[(size_t)row * (2 * SDIM) + SDIM + sglob] = p * su_inv;

        const float g = fmaf(alpha, dlt, selEH) * (2.f * se * su_inv);
        float lg = LOG2F(g);
        lg += __shfl_xor(lg, 1);
        lg += __shfl_xor(lg, 2);
        lg += __shfl_xor(lg, 4);
        lg += __shfl_xor(lg, 8);
        if (sp == 0)
            atomicAdd(&out[(size_t)BROWS * (2 * SDIM) + row], -lg * LN2);
    }
}

// ===========================================================================
// Kernels (three-kernel structure; ~98us of dur_us is harness-fixed, r6).
// ===========================================================================
__global__ __launch_bounds__(256) void prep_a_k(
    const float* __restrict__ W1, unsigned short* __restrict__ W1T,
    const float* __restrict__ logd, float* __restrict__ out)
{
    __shared__ short smem[2112];
    if (blockIdx.x < 256) do_w1t_unit(blockIdx.x, threadIdx.x, W1, W1T, smem);
    else                  do_logd_unit(blockIdx.x - 256, threadIdx.x, logd, out);
}

__global__ __launch_bounds__(256) void mega_k(
    const float* __restrict__ x, const unsigned short* __restrict__ W1T,
    const float* __restrict__ b1, unsigned short* __restrict__ hid_f,
    const float* __restrict__ W2, unsigned short* __restrict__ W2p_f,
    float* __restrict__ out)
{
    __shared__ short smem[16384];             // 32KB (gemm1 staging / pack tile)
    const int bid = blockIdx.x;
    if (bid < 512)        gemm1_tile(bid, threadIdx.x, x, W1T, b1, hid_f, smem);
    else if (bid < 2688)  do_pack_unit(bid - 512, threadIdx.x, W2, W2p_f, smem);
    else                  do_copy_unit(bid - 2688, threadIdx.x, x, out);
}

__global__ __launch_bounds__(256, 3) void gemm2_k(
    const unsigned short* __restrict__ hid_f, const unsigned short* __restrict__ W2p_f,
    const float* __restrict__ b2, const float* __restrict__ x,
    float* __restrict__ out)
{
    __shared__ short smem[18496];             // max(A-half 16384, netS 18496)
    gemm2_tile(blockIdx.x * 64, blockIdx.y, threadIdx.x, hid_f, W2p_f, b2, x, out, smem);
}

// ---------------------------------------------------------------------------
extern "C" void kernel_launch(void* const* d_in, const int* in_sizes, int n_in,
                              void* d_out, int out_size, void* d_ws, size_t ws_size,
                              hipStream_t stream) {
    const float* x    = (const float*)d_in[0];
    const float* logd = (const float*)d_in[1];
    const float* W1   = (const float*)d_in[2];
    const float* b1   = (const float*)d_in[3];
    const float* W2   = (const float*)d_in[4];
    const float* b2   = (const float*)d_in[5];
    float* out = (float*)d_out;

    // ws layout (~17.9 MiB, unchanged offsets)
    char* ws = (char*)d_ws;
    unsigned short* W1T = (unsigned short*)(ws + 32768);     // 512x512 bf16
    unsigned short* W2p = (unsigned short*)(ws + 557056);    // frag-native 8.9MB
    unsigned short* hid = (unsigned short*)(ws + 9469952);   // frag-native 8.4MB

    prep_a_k<<<288, 256, 0, stream>>>(W1, W1T, logd, out);
    mega_k<<<2944, 256, 0, stream>>>(x, W1T, b1, hid, W2, W2p, out);
    gemm2_k<<<dim3(128, 32), 256, 0, stream>>>(hid, W2p, b2, x, out);
}